// Round 18
// baseline (640.569 us; speedup 1.0000x reference)
//
#include <hip/hip_runtime.h>
#include <cmath>

#define WIN 64
#define HID 512
#define BATCH 1024
#define KIN 518

typedef _Float16 f16;
typedef _Float16 half8 __attribute__((ext_vector_type(8)));
typedef float f32x4 __attribute__((ext_vector_type(4)));
typedef unsigned short u16x4 __attribute__((ext_vector_type(4)));

struct Sched { int starts[63]; int ends[63]; };
struct Plan { int ng; int cnt[24]; int g[24]; int tl[24][4]; };

// ---------------------------------------------------------------------------
// prep: blocks 0..1023 = logsig scan (validated r3-r17, writes lsh);
//       blocks 1024..  = f32->f16 weight convert (K zero-padded).
// ---------------------------------------------------------------------------
__global__ __launch_bounds__(256)
void prep(const float* __restrict__ z, Sched sc, ushort* __restrict__ lsh,
          float scale,
          const float* __restrict__ W1, const float* __restrict__ W2,
          const float* __restrict__ W3, ushort* __restrict__ W1h,
          ushort* __restrict__ W2h, ushort* __restrict__ W3h) {
  const int tid = threadIdx.x;
  if (blockIdx.x >= 1024) {
    const int n1 = HID * (576 / 8);
    const int n2 = HID * (HID / 8);
    int i = (blockIdx.x - 1024) * 256 + tid;
    const float* src; ushort* dst; int Ks, Kd;
    if (i < n1)                 { src = W1; dst = W1h; Ks = KIN; Kd = 576; }
    else if (i < n1 + n2)       { src = W2; dst = W2h; Ks = HID; Kd = HID; i -= n1; }
    else if (i < n1 + 2 * n2)   { src = W3; dst = W3h; Ks = HID; Kd = HID; i -= n1 + n2; }
    else return;
    int nblk = Kd >> 3;
    int row = i / nblk, k = (i - row * nblk) * 8;
    half8 v;
#pragma unroll
    for (int j = 0; j < 8; ++j) {
      int kk = k + j;
      float f = (kk < Ks) ? src[(size_t)row * Ks + kk] : 0.f;
      v[j] = (f16)f;
    }
    *(half8*)&dst[(size_t)row * Kd + k] = v;
    return;
  }
  __shared__ float zs[3000];
  __shared__ float Cs[20][3];
  __shared__ float wtot[4][6];
  __shared__ float earr[63][6];
  __shared__ short fe_s[1000];
  const int b = blockIdx.x;
  const int ln = tid & 63, wv = tid >> 6;

  const float4* zrow = (const float4*)(z + (size_t)b * 3000);
  for (int i = tid; i < 750; i += 256) ((float4*)zs)[i] = zrow[i];
  for (int i = tid; i < 1000; i += 256) fe_s[i] = -1;
  if (tid == 0) { Cs[0][0] = 0.f; Cs[0][1] = 0.f; Cs[0][2] = 0.f; }
  __syncthreads();
  if (tid < 63) fe_s[sc.ends[tid]] = (short)tid;
  __syncthreads();

  const int p0 = 4 * tid + 1;
  int myfe[4];
#pragma unroll
  for (int i = 0; i < 4; ++i) myfe[i] = (p0 + i <= 999) ? fe_s[p0 + i] : -1;

  float d0 = 0.f, d1 = 0.f, d2 = 0.f, A0 = 0.f, A1 = 0.f, A2 = 0.f;
  if (p0 <= 999) {
    float b0 = 0.f, b1 = 0.f, b2 = 0.f;
#pragma unroll
    for (int i = 0; i < 4; ++i) {
      int p = p0 + i;
      if (p > 999) break;
      float n0 = b0 + zs[p * 3 + 0] * scale;
      float n1 = b1 + zs[p * 3 + 1] * scale;
      float n2 = b2 + zs[p * 3 + 2] * scale;
      A0 += 0.5f * (b0 * n1 - b1 * n0);
      A1 += 0.5f * (b0 * n2 - b2 * n0);
      A2 += 0.5f * (b1 * n2 - b2 * n1);
      b0 = n0; b1 = n1; b2 = n2;
    }
    d0 = b0; d1 = b1; d2 = b2;
  }

#pragma unroll
  for (int off = 1; off < 64; off <<= 1) {
    float e0 = __shfl(d0, ln - off), e1 = __shfl(d1, ln - off), e2 = __shfl(d2, ln - off);
    float eA0 = __shfl(A0, ln - off), eA1 = __shfl(A1, ln - off), eA2 = __shfl(A2, ln - off);
    if (ln >= off) {
      A0 = eA0 + A0 + 0.5f * (e0 * d1 - e1 * d0);
      A1 = eA1 + A1 + 0.5f * (e0 * d2 - e2 * d0);
      A2 = eA2 + A2 + 0.5f * (e1 * d2 - e2 * d1);
      d0 += e0; d1 += e1; d2 += e2;
    }
  }
  if (ln == 63) {
    wtot[wv][0] = d0; wtot[wv][1] = d1; wtot[wv][2] = d2;
    wtot[wv][3] = A0; wtot[wv][4] = A1; wtot[wv][5] = A2;
  }
  __syncthreads();

  float P0 = 0.f, P1 = 0.f, P2 = 0.f, PA0 = 0.f, PA1 = 0.f, PA2 = 0.f;
  for (int w = 0; w < wv; ++w) {
    float t0 = wtot[w][0], t1 = wtot[w][1], t2 = wtot[w][2];
    PA0 = PA0 + wtot[w][3] + 0.5f * (P0 * t1 - P1 * t0);
    PA1 = PA1 + wtot[w][4] + 0.5f * (P0 * t2 - P2 * t0);
    PA2 = PA2 + wtot[w][5] + 0.5f * (P1 * t2 - P2 * t1);
    P0 += t0; P1 += t1; P2 += t2;
  }
  float L0 = __shfl(d0, ln - 1), L1 = __shfl(d1, ln - 1), L2 = __shfl(d2, ln - 1);
  float LA0 = __shfl(A0, ln - 1), LA1 = __shfl(A1, ln - 1), LA2 = __shfl(A2, ln - 1);
  if (ln == 0) { L0 = L1 = L2 = LA0 = LA1 = LA2 = 0.f; }
  float bp0 = P0 + L0, bp1 = P1 + L1, bp2 = P2 + L2;
  float C0 = PA0 + LA0 + 0.5f * (P0 * L1 - P1 * L0);
  float C1 = PA1 + LA1 + 0.5f * (P0 * L2 - P2 * L0);
  float C2 = PA2 + LA2 + 0.5f * (P1 * L2 - P2 * L1);

  if (p0 <= 999) {
#pragma unroll
    for (int i = 0; i < 4; ++i) {
      int p = p0 + i;
      if (p > 999) break;
      float n0 = bp0 + zs[p * 3 + 0] * scale;
      float n1 = bp1 + zs[p * 3 + 1] * scale;
      float n2 = bp2 + zs[p * 3 + 2] * scale;
      C0 += 0.5f * (bp0 * n1 - bp1 * n0);
      C1 += 0.5f * (bp0 * n2 - bp2 * n0);
      C2 += 0.5f * (bp1 * n2 - bp2 * n1);
      bp0 = n0; bp1 = n1; bp2 = n2;
      if (p % 50 == 0) {
        int s = p / 50;
        Cs[s][0] = C0; Cs[s][1] = C1; Cs[s][2] = C2;
      }
      int k = myfe[i];
      if (k >= 0) {
        earr[k][0] = bp0; earr[k][1] = bp1; earr[k][2] = bp2;
        earr[k][3] = C0;  earr[k][4] = C1;  earr[k][5] = C2;
      }
    }
  }
  __syncthreads();

  if (tid < 63) {
    int s = sc.starts[tid] / 50;
    half8 v = {};
    v[0] = (f16)earr[tid][0]; v[1] = (f16)earr[tid][1]; v[2] = (f16)earr[tid][2];
    v[3] = (f16)(earr[tid][3] - Cs[s][0]);
    v[4] = (f16)(earr[tid][4] - Cs[s][1]);
    v[5] = (f16)(earr[tid][5] - Cs[s][2]);
    half8 zz = {};
    half8* d = (half8*)(lsh + ((size_t)(tid + 1) * BATCH + b) * 64);
    d[0] = v;
#pragma unroll
    for (int q = 1; q < 8; ++q) d[q] = zz;
  } else if (tid == 63) {
    half8 zz = {};
    half8* d = (half8*)(lsh + (size_t)b * 64);
#pragma unroll
    for (int q = 0; q < 8; ++q) d[q] = zz;
  }
}

// ---------------------------------------------------------------------------
// Persistent chain: ALL rounds in ONE launch. Grid 32x4 = 128 co-resident
// blocks (64KB LDS -> <=2/CU). slab = blockIdx.x; linear id == slab (mod 8)
// -> slab's strips AND cross-round carry producer/consumer share one XCD.
// Per round: r16-validated 3-layer LDS-pipelined GEMM + 2 slab flag syncs;
// then a per-XCD 16-block round barrier (monotonic relaxed atomics -- no
// L2-flushing fences). act1/act2 parity-double-buffered (stale-L1 safety).
// ---------------------------------------------------------------------------
__global__ __launch_bounds__(256, 1)
void chain_k(const ushort* __restrict__ lsh,
             const ushort* __restrict__ W1h, const ushort* __restrict__ W2h,
             const ushort* __restrict__ W3h,
             const float* __restrict__ b1, const float* __restrict__ b2,
             const float* __restrict__ b3, const float* __restrict__ Wout,
             ushort* __restrict__ act1a, ushort* __restrict__ act1b,
             ushort* __restrict__ act2a, ushort* __restrict__ act2b,
             ushort* __restrict__ Hall, float* __restrict__ outp,
             int* flags, Plan pl) {
  __shared__ ushort lds[32768];                   // 64KB: 2 x (X 16K | W 16K)
  char* ldsb = (char*)lds;
  const int tid = threadIdx.x;
  const int wv = tid >> 6, ln = tid & 63;
  const int slab = blockIdx.x;                    // 0..31; XCD = slab & 7
  const int bn0 = blockIdx.y * 128;               // col strip
  const int slot = slab >> 3;
  const int b0 = (slab & 7) * 128;                // batch-row base
  const size_t gr0 = (size_t)slab * 128;          // act-row base
  const int xcd = slab & 7;
  const int xr0 = (wv >> 1) * 64, nr0 = (wv & 1) * 64;
  const int l15 = ln & 15, l4 = ln >> 4;
  int lbar = 0;

  f32x4 acc[4][4];

  auto gemm = [&](auto xsrc, const ushort* W, int ldw, int k0, int nk) {
#pragma unroll
    for (int mi = 0; mi < 4; ++mi)
#pragma unroll
      for (int ni = 0; ni < 4; ++ni) acc[mi][ni] = (f32x4){0.f, 0.f, 0.f, 0.f};

    auto stage = [&](int bi, int kt) {
#pragma unroll
      for (int i = 0; i < 4; ++i) {
        int qq = (i * 4 + wv) * 64 + ln;
        int r = qq >> 3, sl = qq & 7, ss = sl ^ (r & 7);
        const ushort* src = xsrc(kt, r, ss);
        __builtin_amdgcn_global_load_lds(
            (const __attribute__((address_space(1))) unsigned int*)src,
            (__attribute__((address_space(3))) unsigned int*)
                (ldsb + bi * 32768 + (i * 4 + wv) * 1024), 16, 0, 0);
      }
#pragma unroll
      for (int i = 0; i < 4; ++i) {
        int qq = (i * 4 + wv) * 64 + ln;
        int r = qq >> 3, sl = qq & 7, ss = sl ^ (r & 7);
        const ushort* src = W + (size_t)(bn0 + r) * ldw + kt * 64 + ss * 8;
        __builtin_amdgcn_global_load_lds(
            (const __attribute__((address_space(1))) unsigned int*)src,
            (__attribute__((address_space(3))) unsigned int*)
                (ldsb + bi * 32768 + 16384 + (i * 4 + wv) * 1024), 16, 0, 0);
      }
    };

    stage(0, k0);
    int cur = 0;
    for (int kt = k0; kt < nk; ++kt) {
      if (kt + 1 < nk) {
        stage(cur ^ 1, kt + 1);
        asm volatile("s_waitcnt vmcnt(8)" ::: "memory");
      } else {
        asm volatile("s_waitcnt vmcnt(0)" ::: "memory");
      }
      __builtin_amdgcn_s_barrier();
      __builtin_amdgcn_sched_barrier(0);
#pragma unroll
      for (int kk = 0; kk < 2; ++kk) {
        half8 xf[4], wf[4];
#pragma unroll
        for (int mi = 0; mi < 4; ++mi) {
          int r = xr0 + mi * 16 + l15;
          int ss = (kk * 4 + l4) ^ (r & 7);
          xf[mi] = *(const half8*)(ldsb + cur * 32768 + r * 128 + ss * 16);
        }
#pragma unroll
        for (int ni = 0; ni < 4; ++ni) {
          int r = nr0 + ni * 16 + l15;
          int ss = (kk * 4 + l4) ^ (r & 7);
          wf[ni] = *(const half8*)(ldsb + cur * 32768 + 16384 + r * 128 + ss * 16);
        }
#pragma unroll
        for (int mi = 0; mi < 4; ++mi)
#pragma unroll
          for (int ni = 0; ni < 4; ++ni)
            acc[mi][ni] = __builtin_amdgcn_mfma_f32_16x16x32_f16(
                wf[ni], xf[mi], acc[mi][ni], 0, 0, 0);
      }
      __builtin_amdgcn_sched_barrier(0);
      asm volatile("s_waitcnt lgkmcnt(0)" ::: "memory");
      __builtin_amdgcn_s_barrier();
      cur ^= 1;
    }
  };

#define EPILOGUE_RELU(BIAS, DST)                                              \
  do {                                                                        \
    _Pragma("unroll")                                                         \
    for (int mi = 0; mi < 4; ++mi) {                                          \
      _Pragma("unroll")                                                       \
      for (int ni = 0; ni < 4; ++ni) {                                        \
        int col = bn0 + nr0 + ni * 16 + l4 * 4;                               \
        float4 bv = *(const float4*)&(BIAS)[col];                             \
        float bb[4] = {bv.x, bv.y, bv.z, bv.w};                               \
        union { f16 h[4]; u16x4 u; } cv;                                      \
        _Pragma("unroll")                                                     \
        for (int j4 = 0; j4 < 4; ++j4) {                                      \
          float v = acc[mi][ni][j4] + bb[j4];                                 \
          v = fmaxf(v, 0.f);                                                  \
          cv.h[j4] = (f16)v;                                                  \
        }                                                                     \
        *(u16x4*)&(DST)[(gr0 + xr0 + mi * 16 + l15) * 512 + col] = cv.u;      \
      }                                                                       \
    }                                                                         \
  } while (0)

#define SYNCSLAB()                                                            \
  do {                                                                        \
    ++lbar;                                                                   \
    asm volatile("s_waitcnt vmcnt(0)" ::: "memory");                          \
    __syncthreads();                                                          \
    if (tid == 0) {                                                           \
      __hip_atomic_fetch_add(&flags[slab], 1, __ATOMIC_RELAXED,               \
                             __HIP_MEMORY_SCOPE_AGENT);                       \
      while (__hip_atomic_load(&flags[slab], __ATOMIC_RELAXED,                \
                               __HIP_MEMORY_SCOPE_AGENT) < 4 * lbar)          \
        __builtin_amdgcn_s_sleep(2);                                          \
    }                                                                         \
    __syncthreads();                                                          \
  } while (0)

  for (int r = 0; r < pl.ng; ++r) {
    const bool active = (slot < pl.cnt[r]);
    if (active) {
      const int t = pl.tl[r][slot];
      const int gated = (t == pl.g[r]) ? 1 : 0;
      const ushort* lbase = lsh + (size_t)t * BATCH * 64;
      ushort* a1 = (r & 1) ? act1b : act1a;
      ushort* a2 = (r & 1) ? act2b : act2a;

      // ---------------- layer 1 ----------------
      if (r == 0) {
        gemm([&](int kt, int rr, int ss) {
          (void)kt; return lbase + (size_t)(b0 + rr) * 64 + ss * 8;
        }, W1h, 576, 8, 9);
      } else {
        const ushort* carry = Hall + (size_t)pl.g[r - 1] * (BATCH * HID);
        gemm([&](int kt, int rr, int ss) {
          int b_ = b0 + rr;
          return (kt < 8) ? carry + (size_t)b_ * HID + kt * 64 + ss * 8
                          : lbase + (size_t)b_ * 64 + ss * 8;
        }, W1h, 576, 0, 9);
      }
      EPILOGUE_RELU(b1, a1);
      SYNCSLAB();

      // ---------------- layer 2 ----------------
      gemm([&](int kt, int rr, int ss) {
        return a1 + (gr0 + rr) * (size_t)HID + kt * 64 + ss * 8;
      }, W2h, 512, 0, 8);
      EPILOGUE_RELU(b2, a2);
      SYNCSLAB();

      // ---------------- layer 3: tanh; fused out-proj; gated -> Hall ------
      gemm([&](int kt, int rr, int ss) {
        return a2 + (gr0 + rr) * (size_t)HID + kt * 64 + ss * 8;
      }, W3h, 512, 0, 8);
      {
        float po[4][3];
#pragma unroll
        for (int mi = 0; mi < 4; ++mi) { po[mi][0] = 0.f; po[mi][1] = 0.f; po[mi][2] = 0.f; }
#pragma unroll
        for (int mi = 0; mi < 4; ++mi) {
#pragma unroll
          for (int ni = 0; ni < 4; ++ni) {
            int col = bn0 + nr0 + ni * 16 + l4 * 4;
            float4 bv = *(const float4*)&b3[col];
            float4 w0 = *(const float4*)&Wout[col];
            float4 w1 = *(const float4*)&Wout[512 + col];
            float4 w2 = *(const float4*)&Wout[1024 + col];
            float bb[4] = {bv.x, bv.y, bv.z, bv.w};
            float W0[4] = {w0.x, w0.y, w0.z, w0.w};
            float W1a[4] = {w1.x, w1.y, w1.z, w1.w};
            float W2a[4] = {w2.x, w2.y, w2.z, w2.w};
            union { f16 h[4]; u16x4 u; } cv;
#pragma unroll
            for (int j4 = 0; j4 < 4; ++j4) {
              float v = acc[mi][ni][j4] + bb[j4];
              float xc = fminf(fmaxf(v, -9.f), 9.f);
              float e = __expf(2.f * xc); v = (e - 1.f) / (e + 1.f);
              cv.h[j4] = (f16)v;
              po[mi][0] += v * W0[j4];
              po[mi][1] += v * W1a[j4];
              po[mi][2] += v * W2a[j4];
            }
            if (gated) {
              size_t hrow = (size_t)t * BATCH + b0 + xr0 + mi * 16 + l15;
              *(u16x4*)&Hall[hrow * 512 + col] = cv.u;
            }
          }
        }
#pragma unroll
        for (int mi = 0; mi < 4; ++mi) {
#pragma unroll
          for (int o = 0; o < 3; ++o) {
            float s = po[mi][o];
            s += __shfl_xor(s, 16);
            s += __shfl_xor(s, 32);
            po[mi][o] = s;
          }
          if (l4 == 0) {
            int row = b0 + xr0 + mi * 16 + l15;
            int y2 = blockIdx.y * 2 + (wv & 1);
            float* op = outp + (((size_t)y2 * WIN + t) * BATCH + row) * 3;
            op[0] = po[mi][0]; op[1] = po[mi][1]; op[2] = po[mi][2];
          }
        }
      }
    }
    // ---------------- per-XCD round barrier (16 blocks) ----------------
    asm volatile("s_waitcnt vmcnt(0)" ::: "memory");
    __syncthreads();
    if (tid == 0) {
      __hip_atomic_fetch_add(&flags[32 + xcd], 1, __ATOMIC_RELAXED,
                             __HIP_MEMORY_SCOPE_AGENT);
      while (__hip_atomic_load(&flags[32 + xcd], __ATOMIC_RELAXED,
                               __HIP_MEMORY_SCOPE_AGENT) < 16 * (r + 1))
        __builtin_amdgcn_s_sleep(2);
    }
    __syncthreads();
  }
#undef EPILOGUE_RELU
#undef SYNCSLAB
}

// ---------------------------------------------------------------------------
// out[b, t, o] = sum_{y2=0..7} outp[y2][t][b][o].
// ---------------------------------------------------------------------------
__global__ __launch_bounds__(256)
void out_sum(const float* __restrict__ outp, float* __restrict__ out) {
  int idx = blockIdx.x * 256 + threadIdx.x;       // (b*WIN + t)*3 + o
  if (idx >= BATCH * WIN * 3) return;
  int o = idx % 3, bt = idx / 3;
  int t = bt % WIN, b = bt / WIN;
  float s = 0.f;
#pragma unroll
  for (int y = 0; y < 8; ++y)
    s += outp[(((size_t)y * WIN + t) * BATCH + b) * 3 + o];
  out[idx] = s;
}

// ---------------------------------------------------------------------------
extern "C" void kernel_launch(void* const* d_in, const int* in_sizes, int n_in,
                              void* d_out, int out_size, void* d_ws, size_t ws_size,
                              hipStream_t stream) {
  (void)n_in; (void)out_size; (void)ws_size; (void)in_sizes;
  const float* z    = (const float*)d_in[0];
  const float* W1   = (const float*)d_in[1];
  const float* b1   = (const float*)d_in[2];
  const float* W2   = (const float*)d_in[3];
  const float* b2   = (const float*)d_in[4];
  const float* W3   = (const float*)d_in[5];
  const float* b3   = (const float*)d_in[6];
  const float* Wout = (const float*)d_in[7];
  float* out = (float*)d_out;

  // ---- replicate _static_schedule exactly (numpy linspace doubles) ----
  double tb[1000], tt[64], tu[20];
  {
    double sb = 1.0 / 999.0; for (int i = 0; i < 1000; ++i) tb[i] = i * sb; tb[999] = 1.0;
    double st = 1.0 / 63.0;  for (int k = 0; k < 64; ++k)  tt[k] = k * st;  tt[63] = 1.0;
    for (int j = 0; j < 20; ++j) tu[j] = tb[50 * j];
  }
  auto ssr = [](const double* a, int n, double v) -> int {
    int lo = 0, hi = n;
    while (lo < hi) { int mid = (lo + hi) >> 1; if (a[mid] <= v) lo = mid + 1; else hi = mid; }
    return lo - 1;
  };
  Sched sc; int gates[64];
  {
    int u_indices[20];
    for (int j = 0; j < 20; ++j) u_indices[j] = ssr(tb, 1000, tu[j]);
    double u_times[80]; int nut = 0; int last = -1;
    for (int k = 1; k < 64; ++k) {
      int it = ssr(tb, 1000, tt[k]);
      int iu = ssr(tu, 20, tt[k]); if (iu < 0) iu = 0;
      if (iu != last) { u_times[nut++] = tu[iu]; last = iu; }
      sc.starts[k - 1] = u_indices[iu];
      sc.ends[k - 1] = it;
    }
    u_times[nut++] = tt[63];
    int qh = 0;
    for (int k = 0; k < 64; ++k) {
      if (qh < nut && tt[k] >= u_times[qh]) { ++qh; gates[k] = 1; } else gates[k] = 0;
    }
  }
  int seg[64], g[64], ng = 0, jlast = -1;
  for (int t = 0; t < WIN; ++t) {
    seg[t] = jlast;
    if (gates[t]) { g[ng] = t; jlast = ng; ++ng; }
  }

  // ---- build device plan ----
  Plan pl; pl.ng = ng;
  for (int r = 0; r < ng && r < 24; ++r) {
    int cnt = 0;
    for (int t = 0; t < WIN && cnt < 4; ++t)
      if (seg[t] == r - 1) pl.tl[r][cnt++] = t;
    pl.cnt[r] = cnt;
    pl.g[r] = g[r];
    for (int i = cnt; i < 4; ++i) pl.tl[r][i] = 0;
  }

  // ---- workspace carve ----
  char* p = (char*)d_ws;
  int* flags    = (int*)p;    p += 64 * 4;
  ushort* lsh   = (ushort*)p; p += (size_t)WIN * BATCH * 64 * 2;       // 8.4 MB
  ushort* W1h   = (ushort*)p; p += (size_t)HID * 576 * 2;
  ushort* W2h   = (ushort*)p; p += (size_t)HID * HID * 2;
  ushort* W3h   = (ushort*)p; p += (size_t)HID * HID * 2;
  ushort* Hall  = (ushort*)p; p += (size_t)WIN * BATCH * HID * 2;      // 67 MB
  ushort* act1a = (ushort*)p; p += (size_t)4 * BATCH * HID * 2;        // 4.2 MB
  ushort* act1b = (ushort*)p; p += (size_t)4 * BATCH * HID * 2;
  ushort* act2a = (ushort*)p; p += (size_t)4 * BATCH * HID * 2;
  ushort* act2b = (ushort*)p; p += (size_t)4 * BATCH * HID * 2;
  float* outp   = (float*)p;  p += (size_t)8 * WIN * BATCH * 3 * 4;    // 6.3 MB

  hipMemsetAsync(flags, 0, 64 * 4, stream);

  float scale = (float)std::sqrt(1.0 / 999.0);
  prep<<<1024 + 400, 256, 0, stream>>>(z, sc, lsh, scale,
                                       W1, W2, W3, W1h, W2h, W3h);

  // ---- persistent chain: ONE launch for all rounds ----
  chain_k<<<dim3(32, 4), 256, 0, stream>>>(lsh, W1h, W2h, W3h,
                                           b1, b2, b3, Wout,
                                           act1a, act1b, act2a, act2b,
                                           Hall, outp, flags, pl);

  out_sum<<<(BATCH * WIN * 3 + 255) / 256, 256, 0, stream>>>(outp, out);
}

// Round 19
// 619.018 us; speedup vs baseline: 1.0348x; 1.0348x over previous
//
#include <hip/hip_runtime.h>
#include <cmath>

#define WIN 64
#define HID 512
#define BATCH 1024
#define KIN 518

typedef _Float16 f16;
typedef _Float16 half8 __attribute__((ext_vector_type(8)));
typedef float f32x4 __attribute__((ext_vector_type(4)));
typedef unsigned short u16x4 __attribute__((ext_vector_type(4)));

struct Sched { int starts[63]; int ends[63]; };
struct Plan { int ng; int cnt[24]; int g[24]; int tl[24][4]; };

// ---------------------------------------------------------------------------
// prep: blocks 0..1023 = logsig scan (validated r3-r18, writes lsh);
//       blocks 1024..  = f32->f16 weight convert (K zero-padded).
// ---------------------------------------------------------------------------
__global__ __launch_bounds__(256)
void prep(const float* __restrict__ z, Sched sc, ushort* __restrict__ lsh,
          float scale,
          const float* __restrict__ W1, const float* __restrict__ W2,
          const float* __restrict__ W3, ushort* __restrict__ W1h,
          ushort* __restrict__ W2h, ushort* __restrict__ W3h) {
  const int tid = threadIdx.x;
  if (blockIdx.x >= 1024) {
    const int n1 = HID * (576 / 8);
    const int n2 = HID * (HID / 8);
    int i = (blockIdx.x - 1024) * 256 + tid;
    const float* src; ushort* dst; int Ks, Kd;
    if (i < n1)                 { src = W1; dst = W1h; Ks = KIN; Kd = 576; }
    else if (i < n1 + n2)       { src = W2; dst = W2h; Ks = HID; Kd = HID; i -= n1; }
    else if (i < n1 + 2 * n2)   { src = W3; dst = W3h; Ks = HID; Kd = HID; i -= n1 + n2; }
    else return;
    int nblk = Kd >> 3;
    int row = i / nblk, k = (i - row * nblk) * 8;
    half8 v;
#pragma unroll
    for (int j = 0; j < 8; ++j) {
      int kk = k + j;
      float f = (kk < Ks) ? src[(size_t)row * Ks + kk] : 0.f;
      v[j] = (f16)f;
    }
    *(half8*)&dst[(size_t)row * Kd + k] = v;
    return;
  }
  __shared__ float zs[3000];
  __shared__ float Cs[20][3];
  __shared__ float wtot[4][6];
  __shared__ float earr[63][6];
  __shared__ short fe_s[1000];
  const int b = blockIdx.x;
  const int ln = tid & 63, wv = tid >> 6;

  const float4* zrow = (const float4*)(z + (size_t)b * 3000);
  for (int i = tid; i < 750; i += 256) ((float4*)zs)[i] = zrow[i];
  for (int i = tid; i < 1000; i += 256) fe_s[i] = -1;
  if (tid == 0) { Cs[0][0] = 0.f; Cs[0][1] = 0.f; Cs[0][2] = 0.f; }
  __syncthreads();
  if (tid < 63) fe_s[sc.ends[tid]] = (short)tid;
  __syncthreads();

  const int p0 = 4 * tid + 1;
  int myfe[4];
#pragma unroll
  for (int i = 0; i < 4; ++i) myfe[i] = (p0 + i <= 999) ? fe_s[p0 + i] : -1;

  float d0 = 0.f, d1 = 0.f, d2 = 0.f, A0 = 0.f, A1 = 0.f, A2 = 0.f;
  if (p0 <= 999) {
    float b0 = 0.f, b1 = 0.f, b2 = 0.f;
#pragma unroll
    for (int i = 0; i < 4; ++i) {
      int p = p0 + i;
      if (p > 999) break;
      float n0 = b0 + zs[p * 3 + 0] * scale;
      float n1 = b1 + zs[p * 3 + 1] * scale;
      float n2 = b2 + zs[p * 3 + 2] * scale;
      A0 += 0.5f * (b0 * n1 - b1 * n0);
      A1 += 0.5f * (b0 * n2 - b2 * n0);
      A2 += 0.5f * (b1 * n2 - b2 * n1);
      b0 = n0; b1 = n1; b2 = n2;
    }
    d0 = b0; d1 = b1; d2 = b2;
  }

#pragma unroll
  for (int off = 1; off < 64; off <<= 1) {
    float e0 = __shfl(d0, ln - off), e1 = __shfl(d1, ln - off), e2 = __shfl(d2, ln - off);
    float eA0 = __shfl(A0, ln - off), eA1 = __shfl(A1, ln - off), eA2 = __shfl(A2, ln - off);
    if (ln >= off) {
      A0 = eA0 + A0 + 0.5f * (e0 * d1 - e1 * d0);
      A1 = eA1 + A1 + 0.5f * (e0 * d2 - e2 * d0);
      A2 = eA2 + A2 + 0.5f * (e1 * d2 - e2 * d1);
      d0 += e0; d1 += e1; d2 += e2;
    }
  }
  if (ln == 63) {
    wtot[wv][0] = d0; wtot[wv][1] = d1; wtot[wv][2] = d2;
    wtot[wv][3] = A0; wtot[wv][4] = A1; wtot[wv][5] = A2;
  }
  __syncthreads();

  float P0 = 0.f, P1 = 0.f, P2 = 0.f, PA0 = 0.f, PA1 = 0.f, PA2 = 0.f;
  for (int w = 0; w < wv; ++w) {
    float t0 = wtot[w][0], t1 = wtot[w][1], t2 = wtot[w][2];
    PA0 = PA0 + wtot[w][3] + 0.5f * (P0 * t1 - P1 * t0);
    PA1 = PA1 + wtot[w][4] + 0.5f * (P0 * t2 - P2 * t0);
    PA2 = PA2 + wtot[w][5] + 0.5f * (P1 * t2 - P2 * t1);
    P0 += t0; P1 += t1; P2 += t2;
  }
  float L0 = __shfl(d0, ln - 1), L1 = __shfl(d1, ln - 1), L2 = __shfl(d2, ln - 1);
  float LA0 = __shfl(A0, ln - 1), LA1 = __shfl(A1, ln - 1), LA2 = __shfl(A2, ln - 1);
  if (ln == 0) { L0 = L1 = L2 = LA0 = LA1 = LA2 = 0.f; }
  float bp0 = P0 + L0, bp1 = P1 + L1, bp2 = P2 + L2;
  float C0 = PA0 + LA0 + 0.5f * (P0 * L1 - P1 * L0);
  float C1 = PA1 + LA1 + 0.5f * (P0 * L2 - P2 * L0);
  float C2 = PA2 + LA2 + 0.5f * (P1 * L2 - P2 * L1);

  if (p0 <= 999) {
#pragma unroll
    for (int i = 0; i < 4; ++i) {
      int p = p0 + i;
      if (p > 999) break;
      float n0 = bp0 + zs[p * 3 + 0] * scale;
      float n1 = bp1 + zs[p * 3 + 1] * scale;
      float n2 = bp2 + zs[p * 3 + 2] * scale;
      C0 += 0.5f * (bp0 * n1 - bp1 * n0);
      C1 += 0.5f * (bp0 * n2 - bp2 * n0);
      C2 += 0.5f * (bp1 * n2 - bp2 * n1);
      bp0 = n0; bp1 = n1; bp2 = n2;
      if (p % 50 == 0) {
        int s = p / 50;
        Cs[s][0] = C0; Cs[s][1] = C1; Cs[s][2] = C2;
      }
      int k = myfe[i];
      if (k >= 0) {
        earr[k][0] = bp0; earr[k][1] = bp1; earr[k][2] = bp2;
        earr[k][3] = C0;  earr[k][4] = C1;  earr[k][5] = C2;
      }
    }
  }
  __syncthreads();

  if (tid < 63) {
    int s = sc.starts[tid] / 50;
    half8 v = {};
    v[0] = (f16)earr[tid][0]; v[1] = (f16)earr[tid][1]; v[2] = (f16)earr[tid][2];
    v[3] = (f16)(earr[tid][3] - Cs[s][0]);
    v[4] = (f16)(earr[tid][4] - Cs[s][1]);
    v[5] = (f16)(earr[tid][5] - Cs[s][2]);
    half8 zz = {};
    half8* d = (half8*)(lsh + ((size_t)(tid + 1) * BATCH + b) * 64);
    d[0] = v;
#pragma unroll
    for (int q = 1; q < 8; ++q) d[q] = zz;
  } else if (tid == 63) {
    half8 zz = {};
    half8* d = (half8*)(lsh + (size_t)b * 64);
#pragma unroll
    for (int q = 0; q < 8; ++q) d[q] = zz;
  }
}

// ---------------------------------------------------------------------------
// Persistent chain, FINE-GRAINED cross-round sync: the only cross-slab
// dependency is round r's carry read of Hall[g[r-1]] <- gated slab (same
// slab&7) of round r-1. Producer strips bump flags[32+xcd] after layer-3
// stores drain; consumers spin to 4r before layer 1. act1/act2 are
// slab-private (self-ordered via per-slab SYNCSLAB); Hall slots write-once;
// outp slots disjoint. No global/round barrier -> rounds pipeline.
// ---------------------------------------------------------------------------
__global__ __launch_bounds__(256, 1)
void chain_k(const ushort* __restrict__ lsh,
             const ushort* __restrict__ W1h, const ushort* __restrict__ W2h,
             const ushort* __restrict__ W3h,
             const float* __restrict__ b1, const float* __restrict__ b2,
             const float* __restrict__ b3, const float* __restrict__ Wout,
             ushort* __restrict__ act1a, ushort* __restrict__ act1b,
             ushort* __restrict__ act2a, ushort* __restrict__ act2b,
             ushort* __restrict__ Hall, float* __restrict__ outp,
             int* flags, Plan pl) {
  __shared__ ushort lds[32768];                   // 64KB: 2 x (X 16K | W 16K)
  char* ldsb = (char*)lds;
  const int tid = threadIdx.x;
  const int wv = tid >> 6, ln = tid & 63;
  const int slab = blockIdx.x;                    // 0..31; XCD = slab & 7
  const int bn0 = blockIdx.y * 128;               // col strip
  const int slot = slab >> 3;
  const int b0 = (slab & 7) * 128;                // batch-row base
  const size_t gr0 = (size_t)slab * 128;          // act-row base
  const int xcd = slab & 7;
  const int xr0 = (wv >> 1) * 64, nr0 = (wv & 1) * 64;
  const int l15 = ln & 15, l4 = ln >> 4;
  int lbar = 0;

  f32x4 acc[4][4];

  auto gemm = [&](auto xsrc, const ushort* W, int ldw, int k0, int nk) {
#pragma unroll
    for (int mi = 0; mi < 4; ++mi)
#pragma unroll
      for (int ni = 0; ni < 4; ++ni) acc[mi][ni] = (f32x4){0.f, 0.f, 0.f, 0.f};

    auto stage = [&](int bi, int kt) {
#pragma unroll
      for (int i = 0; i < 4; ++i) {
        int qq = (i * 4 + wv) * 64 + ln;
        int r = qq >> 3, sl = qq & 7, ss = sl ^ (r & 7);
        const ushort* src = xsrc(kt, r, ss);
        __builtin_amdgcn_global_load_lds(
            (const __attribute__((address_space(1))) unsigned int*)src,
            (__attribute__((address_space(3))) unsigned int*)
                (ldsb + bi * 32768 + (i * 4 + wv) * 1024), 16, 0, 0);
      }
#pragma unroll
      for (int i = 0; i < 4; ++i) {
        int qq = (i * 4 + wv) * 64 + ln;
        int r = qq >> 3, sl = qq & 7, ss = sl ^ (r & 7);
        const ushort* src = W + (size_t)(bn0 + r) * ldw + kt * 64 + ss * 8;
        __builtin_amdgcn_global_load_lds(
            (const __attribute__((address_space(1))) unsigned int*)src,
            (__attribute__((address_space(3))) unsigned int*)
                (ldsb + bi * 32768 + 16384 + (i * 4 + wv) * 1024), 16, 0, 0);
      }
    };

    stage(0, k0);
    int cur = 0;
    for (int kt = k0; kt < nk; ++kt) {
      if (kt + 1 < nk) {
        stage(cur ^ 1, kt + 1);
        asm volatile("s_waitcnt vmcnt(8)" ::: "memory");
      } else {
        asm volatile("s_waitcnt vmcnt(0)" ::: "memory");
      }
      __builtin_amdgcn_s_barrier();
      __builtin_amdgcn_sched_barrier(0);
#pragma unroll
      for (int kk = 0; kk < 2; ++kk) {
        half8 xf[4], wf[4];
#pragma unroll
        for (int mi = 0; mi < 4; ++mi) {
          int r = xr0 + mi * 16 + l15;
          int ss = (kk * 4 + l4) ^ (r & 7);
          xf[mi] = *(const half8*)(ldsb + cur * 32768 + r * 128 + ss * 16);
        }
#pragma unroll
        for (int ni = 0; ni < 4; ++ni) {
          int r = nr0 + ni * 16 + l15;
          int ss = (kk * 4 + l4) ^ (r & 7);
          wf[ni] = *(const half8*)(ldsb + cur * 32768 + 16384 + r * 128 + ss * 16);
        }
#pragma unroll
        for (int mi = 0; mi < 4; ++mi)
#pragma unroll
          for (int ni = 0; ni < 4; ++ni)
            acc[mi][ni] = __builtin_amdgcn_mfma_f32_16x16x32_f16(
                wf[ni], xf[mi], acc[mi][ni], 0, 0, 0);
      }
      __builtin_amdgcn_sched_barrier(0);
      asm volatile("s_waitcnt lgkmcnt(0)" ::: "memory");
      __builtin_amdgcn_s_barrier();
      cur ^= 1;
    }
  };

#define EPILOGUE_RELU(BIAS, DST)                                              \
  do {                                                                        \
    _Pragma("unroll")                                                         \
    for (int mi = 0; mi < 4; ++mi) {                                          \
      _Pragma("unroll")                                                       \
      for (int ni = 0; ni < 4; ++ni) {                                        \
        int col = bn0 + nr0 + ni * 16 + l4 * 4;                               \
        float4 bv = *(const float4*)&(BIAS)[col];                             \
        float bb[4] = {bv.x, bv.y, bv.z, bv.w};                               \
        union { f16 h[4]; u16x4 u; } cv;                                      \
        _Pragma("unroll")                                                     \
        for (int j4 = 0; j4 < 4; ++j4) {                                      \
          float v = acc[mi][ni][j4] + bb[j4];                                 \
          v = fmaxf(v, 0.f);                                                  \
          cv.h[j4] = (f16)v;                                                  \
        }                                                                     \
        *(u16x4*)&(DST)[(gr0 + xr0 + mi * 16 + l15) * 512 + col] = cv.u;      \
      }                                                                       \
    }                                                                         \
  } while (0)

#define SYNCSLAB()                                                            \
  do {                                                                        \
    ++lbar;                                                                   \
    asm volatile("s_waitcnt vmcnt(0)" ::: "memory");                          \
    __syncthreads();                                                          \
    if (tid == 0) {                                                           \
      __hip_atomic_fetch_add(&flags[slab], 1, __ATOMIC_RELAXED,               \
                             __HIP_MEMORY_SCOPE_AGENT);                       \
      while (__hip_atomic_load(&flags[slab], __ATOMIC_RELAXED,                \
                               __HIP_MEMORY_SCOPE_AGENT) < 4 * lbar)          \
        __builtin_amdgcn_s_sleep(2);                                          \
    }                                                                         \
    __syncthreads();                                                          \
  } while (0)

  for (int r = 0; r < pl.ng; ++r) {
    const bool active = (slot < pl.cnt[r]);
    if (active) {
      const int t = pl.tl[r][slot];
      const int gated = (t == pl.g[r]) ? 1 : 0;
      const ushort* lbase = lsh + (size_t)t * BATCH * 64;
      ushort* a1 = (r & 1) ? act1b : act1a;
      ushort* a2 = (r & 1) ? act2b : act2a;

      // ---- wait for carry producer (gated slab of round r-1, same XCD) ----
      if (r > 0) {
        __syncthreads();
        if (tid == 0) {
          while (__hip_atomic_load(&flags[32 + xcd], __ATOMIC_RELAXED,
                                   __HIP_MEMORY_SCOPE_AGENT) < 4 * r)
            __builtin_amdgcn_s_sleep(2);
        }
        __syncthreads();
      }

      // ---------------- layer 1 ----------------
      if (r == 0) {
        gemm([&](int kt, int rr, int ss) {
          (void)kt; return lbase + (size_t)(b0 + rr) * 64 + ss * 8;
        }, W1h, 576, 8, 9);
      } else {
        const ushort* carry = Hall + (size_t)pl.g[r - 1] * (BATCH * HID);
        gemm([&](int kt, int rr, int ss) {
          int b_ = b0 + rr;
          return (kt < 8) ? carry + (size_t)b_ * HID + kt * 64 + ss * 8
                          : lbase + (size_t)b_ * 64 + ss * 8;
        }, W1h, 576, 0, 9);
      }
      EPILOGUE_RELU(b1, a1);
      SYNCSLAB();

      // ---------------- layer 2 ----------------
      gemm([&](int kt, int rr, int ss) {
        return a1 + (gr0 + rr) * (size_t)HID + kt * 64 + ss * 8;
      }, W2h, 512, 0, 8);
      EPILOGUE_RELU(b2, a2);
      SYNCSLAB();

      // ---------------- layer 3: tanh; fused out-proj; gated -> Hall ------
      gemm([&](int kt, int rr, int ss) {
        return a2 + (gr0 + rr) * (size_t)HID + kt * 64 + ss * 8;
      }, W3h, 512, 0, 8);
      {
        float po[4][3];
#pragma unroll
        for (int mi = 0; mi < 4; ++mi) { po[mi][0] = 0.f; po[mi][1] = 0.f; po[mi][2] = 0.f; }
#pragma unroll
        for (int mi = 0; mi < 4; ++mi) {
#pragma unroll
          for (int ni = 0; ni < 4; ++ni) {
            int col = bn0 + nr0 + ni * 16 + l4 * 4;
            float4 bv = *(const float4*)&b3[col];
            float4 w0 = *(const float4*)&Wout[col];
            float4 w1 = *(const float4*)&Wout[512 + col];
            float4 w2 = *(const float4*)&Wout[1024 + col];
            float bb[4] = {bv.x, bv.y, bv.z, bv.w};
            float W0[4] = {w0.x, w0.y, w0.z, w0.w};
            float W1a[4] = {w1.x, w1.y, w1.z, w1.w};
            float W2a[4] = {w2.x, w2.y, w2.z, w2.w};
            union { f16 h[4]; u16x4 u; } cv;
#pragma unroll
            for (int j4 = 0; j4 < 4; ++j4) {
              float v = acc[mi][ni][j4] + bb[j4];
              float xc = fminf(fmaxf(v, -9.f), 9.f);
              float e = __expf(2.f * xc); v = (e - 1.f) / (e + 1.f);
              cv.h[j4] = (f16)v;
              po[mi][0] += v * W0[j4];
              po[mi][1] += v * W1a[j4];
              po[mi][2] += v * W2a[j4];
            }
            if (gated) {
              size_t hrow = (size_t)t * BATCH + b0 + xr0 + mi * 16 + l15;
              *(u16x4*)&Hall[hrow * 512 + col] = cv.u;
            }
          }
        }
#pragma unroll
        for (int mi = 0; mi < 4; ++mi) {
#pragma unroll
          for (int o = 0; o < 3; ++o) {
            float s = po[mi][o];
            s += __shfl_xor(s, 16);
            s += __shfl_xor(s, 32);
            po[mi][o] = s;
          }
          if (l4 == 0) {
            int row = b0 + xr0 + mi * 16 + l15;
            int y2 = blockIdx.y * 2 + (wv & 1);
            float* op = outp + (((size_t)y2 * WIN + t) * BATCH + row) * 3;
            op[0] = po[mi][0]; op[1] = po[mi][1]; op[2] = po[mi][2];
          }
        }
      }
      // ---- producer signal: gated slab announces Hall[g[r]] ready ----
      if (gated) {
        asm volatile("s_waitcnt vmcnt(0)" ::: "memory");
        __syncthreads();
        if (tid == 0)
          __hip_atomic_fetch_add(&flags[32 + xcd], 1, __ATOMIC_RELAXED,
                                 __HIP_MEMORY_SCOPE_AGENT);
      }
    }
  }
}

// ---------------------------------------------------------------------------
// out[b, t, o] = sum_{y2=0..7} outp[y2][t][b][o].
// ---------------------------------------------------------------------------
__global__ __launch_bounds__(256)
void out_sum(const float* __restrict__ outp, float* __restrict__ out) {
  int idx = blockIdx.x * 256 + threadIdx.x;       // (b*WIN + t)*3 + o
  if (idx >= BATCH * WIN * 3) return;
  int o = idx % 3, bt = idx / 3;
  int t = bt % WIN, b = bt / WIN;
  float s = 0.f;
#pragma unroll
  for (int y = 0; y < 8; ++y)
    s += outp[(((size_t)y * WIN + t) * BATCH + b) * 3 + o];
  out[idx] = s;
}

// ---------------------------------------------------------------------------
extern "C" void kernel_launch(void* const* d_in, const int* in_sizes, int n_in,
                              void* d_out, int out_size, void* d_ws, size_t ws_size,
                              hipStream_t stream) {
  (void)n_in; (void)out_size; (void)ws_size; (void)in_sizes;
  const float* z    = (const float*)d_in[0];
  const float* W1   = (const float*)d_in[1];
  const float* b1   = (const float*)d_in[2];
  const float* W2   = (const float*)d_in[3];
  const float* b2   = (const float*)d_in[4];
  const float* W3   = (const float*)d_in[5];
  const float* b3   = (const float*)d_in[6];
  const float* Wout = (const float*)d_in[7];
  float* out = (float*)d_out;

  // ---- replicate _static_schedule exactly (numpy linspace doubles) ----
  double tb[1000], tt[64], tu[20];
  {
    double sb = 1.0 / 999.0; for (int i = 0; i < 1000; ++i) tb[i] = i * sb; tb[999] = 1.0;
    double st = 1.0 / 63.0;  for (int k = 0; k < 64; ++k)  tt[k] = k * st;  tt[63] = 1.0;
    for (int j = 0; j < 20; ++j) tu[j] = tb[50 * j];
  }
  auto ssr = [](const double* a, int n, double v) -> int {
    int lo = 0, hi = n;
    while (lo < hi) { int mid = (lo + hi) >> 1; if (a[mid] <= v) lo = mid + 1; else hi = mid; }
    return lo - 1;
  };
  Sched sc; int gates[64];
  {
    int u_indices[20];
    for (int j = 0; j < 20; ++j) u_indices[j] = ssr(tb, 1000, tu[j]);
    double u_times[80]; int nut = 0; int last = -1;
    for (int k = 1; k < 64; ++k) {
      int it = ssr(tb, 1000, tt[k]);
      int iu = ssr(tu, 20, tt[k]); if (iu < 0) iu = 0;
      if (iu != last) { u_times[nut++] = tu[iu]; last = iu; }
      sc.starts[k - 1] = u_indices[iu];
      sc.ends[k - 1] = it;
    }
    u_times[nut++] = tt[63];
    int qh = 0;
    for (int k = 0; k < 64; ++k) {
      if (qh < nut && tt[k] >= u_times[qh]) { ++qh; gates[k] = 1; } else gates[k] = 0;
    }
  }
  int seg[64], g[64], ng = 0, jlast = -1;
  for (int t = 0; t < WIN; ++t) {
    seg[t] = jlast;
    if (gates[t]) { g[ng] = t; jlast = ng; ++ng; }
  }

  // ---- build device plan ----
  Plan pl; pl.ng = ng;
  for (int r = 0; r < ng && r < 24; ++r) {
    int cnt = 0;
    for (int t = 0; t < WIN && cnt < 4; ++t)
      if (seg[t] == r - 1) pl.tl[r][cnt++] = t;
    pl.cnt[r] = cnt;
    pl.g[r] = g[r];
    for (int i = cnt; i < 4; ++i) pl.tl[r][i] = 0;
  }

  // ---- workspace carve ----
  char* p = (char*)d_ws;
  int* flags    = (int*)p;    p += 64 * 4;
  ushort* lsh   = (ushort*)p; p += (size_t)WIN * BATCH * 64 * 2;       // 8.4 MB
  ushort* W1h   = (ushort*)p; p += (size_t)HID * 576 * 2;
  ushort* W2h   = (ushort*)p; p += (size_t)HID * HID * 2;
  ushort* W3h   = (ushort*)p; p += (size_t)HID * HID * 2;
  ushort* Hall  = (ushort*)p; p += (size_t)WIN * BATCH * HID * 2;      // 67 MB
  ushort* act1a = (ushort*)p; p += (size_t)4 * BATCH * HID * 2;        // 4.2 MB
  ushort* act1b = (ushort*)p; p += (size_t)4 * BATCH * HID * 2;
  ushort* act2a = (ushort*)p; p += (size_t)4 * BATCH * HID * 2;
  ushort* act2b = (ushort*)p; p += (size_t)4 * BATCH * HID * 2;
  float* outp   = (float*)p;  p += (size_t)8 * WIN * BATCH * 3 * 4;    // 6.3 MB

  hipMemsetAsync(flags, 0, 64 * 4, stream);

  float scale = (float)std::sqrt(1.0 / 999.0);
  prep<<<1024 + 400, 256, 0, stream>>>(z, sc, lsh, scale,
                                       W1, W2, W3, W1h, W2h, W3h);

  // ---- persistent chain: ONE launch, fine-grained producer flags ----
  chain_k<<<dim3(32, 4), 256, 0, stream>>>(lsh, W1h, W2h, W3h,
                                           b1, b2, b3, Wout,
                                           act1a, act1b, act2a, act2b,
                                           Hall, outp, flags, pl);

  out_sum<<<(BATCH * WIN * 3 + 255) / 256, 256, 0, stream>>>(outp, out);
}

// Round 20
// 559.453 us; speedup vs baseline: 1.1450x; 1.1065x over previous
//
#include <hip/hip_runtime.h>
#include <cmath>

#define WIN 64
#define HID 512
#define BATCH 1024
#define KIN 518

typedef _Float16 f16;
typedef _Float16 half8 __attribute__((ext_vector_type(8)));
typedef float f32x4 __attribute__((ext_vector_type(4)));
typedef unsigned short u16x4 __attribute__((ext_vector_type(4)));

struct Sched { int starts[63]; int ends[63]; };
struct Plan { int ng; int cnt[24]; int g[24]; int tl[24][4]; };

// ---------------------------------------------------------------------------
// prep: blocks 0..1023 = logsig scan (validated r3-r19, writes lsh);
//       blocks 1024..  = f32->f16 weight convert (K zero-padded).
// ---------------------------------------------------------------------------
__global__ __launch_bounds__(256)
void prep(const float* __restrict__ z, Sched sc, ushort* __restrict__ lsh,
          float scale,
          const float* __restrict__ W1, const float* __restrict__ W2,
          const float* __restrict__ W3, ushort* __restrict__ W1h,
          ushort* __restrict__ W2h, ushort* __restrict__ W3h) {
  const int tid = threadIdx.x;
  if (blockIdx.x >= 1024) {
    const int n1 = HID * (576 / 8);
    const int n2 = HID * (HID / 8);
    int i = (blockIdx.x - 1024) * 256 + tid;
    const float* src; ushort* dst; int Ks, Kd;
    if (i < n1)                 { src = W1; dst = W1h; Ks = KIN; Kd = 576; }
    else if (i < n1 + n2)       { src = W2; dst = W2h; Ks = HID; Kd = HID; i -= n1; }
    else if (i < n1 + 2 * n2)   { src = W3; dst = W3h; Ks = HID; Kd = HID; i -= n1 + n2; }
    else return;
    int nblk = Kd >> 3;
    int row = i / nblk, k = (i - row * nblk) * 8;
    half8 v;
#pragma unroll
    for (int j = 0; j < 8; ++j) {
      int kk = k + j;
      float f = (kk < Ks) ? src[(size_t)row * Ks + kk] : 0.f;
      v[j] = (f16)f;
    }
    *(half8*)&dst[(size_t)row * Kd + k] = v;
    return;
  }
  __shared__ float zs[3000];
  __shared__ float Cs[20][3];
  __shared__ float wtot[4][6];
  __shared__ float earr[63][6];
  __shared__ short fe_s[1000];
  const int b = blockIdx.x;
  const int ln = tid & 63, wv = tid >> 6;

  const float4* zrow = (const float4*)(z + (size_t)b * 3000);
  for (int i = tid; i < 750; i += 256) ((float4*)zs)[i] = zrow[i];
  for (int i = tid; i < 1000; i += 256) fe_s[i] = -1;
  if (tid == 0) { Cs[0][0] = 0.f; Cs[0][1] = 0.f; Cs[0][2] = 0.f; }
  __syncthreads();
  if (tid < 63) fe_s[sc.ends[tid]] = (short)tid;
  __syncthreads();

  const int p0 = 4 * tid + 1;
  int myfe[4];
#pragma unroll
  for (int i = 0; i < 4; ++i) myfe[i] = (p0 + i <= 999) ? fe_s[p0 + i] : -1;

  float d0 = 0.f, d1 = 0.f, d2 = 0.f, A0 = 0.f, A1 = 0.f, A2 = 0.f;
  if (p0 <= 999) {
    float b0 = 0.f, b1 = 0.f, b2 = 0.f;
#pragma unroll
    for (int i = 0; i < 4; ++i) {
      int p = p0 + i;
      if (p > 999) break;
      float n0 = b0 + zs[p * 3 + 0] * scale;
      float n1 = b1 + zs[p * 3 + 1] * scale;
      float n2 = b2 + zs[p * 3 + 2] * scale;
      A0 += 0.5f * (b0 * n1 - b1 * n0);
      A1 += 0.5f * (b0 * n2 - b2 * n0);
      A2 += 0.5f * (b1 * n2 - b2 * n1);
      b0 = n0; b1 = n1; b2 = n2;
    }
    d0 = b0; d1 = b1; d2 = b2;
  }

#pragma unroll
  for (int off = 1; off < 64; off <<= 1) {
    float e0 = __shfl(d0, ln - off), e1 = __shfl(d1, ln - off), e2 = __shfl(d2, ln - off);
    float eA0 = __shfl(A0, ln - off), eA1 = __shfl(A1, ln - off), eA2 = __shfl(A2, ln - off);
    if (ln >= off) {
      A0 = eA0 + A0 + 0.5f * (e0 * d1 - e1 * d0);
      A1 = eA1 + A1 + 0.5f * (e0 * d2 - e2 * d0);
      A2 = eA2 + A2 + 0.5f * (e1 * d2 - e2 * d1);
      d0 += e0; d1 += e1; d2 += e2;
    }
  }
  if (ln == 63) {
    wtot[wv][0] = d0; wtot[wv][1] = d1; wtot[wv][2] = d2;
    wtot[wv][3] = A0; wtot[wv][4] = A1; wtot[wv][5] = A2;
  }
  __syncthreads();

  float P0 = 0.f, P1 = 0.f, P2 = 0.f, PA0 = 0.f, PA1 = 0.f, PA2 = 0.f;
  for (int w = 0; w < wv; ++w) {
    float t0 = wtot[w][0], t1 = wtot[w][1], t2 = wtot[w][2];
    PA0 = PA0 + wtot[w][3] + 0.5f * (P0 * t1 - P1 * t0);
    PA1 = PA1 + wtot[w][4] + 0.5f * (P0 * t2 - P2 * t0);
    PA2 = PA2 + wtot[w][5] + 0.5f * (P1 * t2 - P2 * t1);
    P0 += t0; P1 += t1; P2 += t2;
  }
  float L0 = __shfl(d0, ln - 1), L1 = __shfl(d1, ln - 1), L2 = __shfl(d2, ln - 1);
  float LA0 = __shfl(A0, ln - 1), LA1 = __shfl(A1, ln - 1), LA2 = __shfl(A2, ln - 1);
  if (ln == 0) { L0 = L1 = L2 = LA0 = LA1 = LA2 = 0.f; }
  float bp0 = P0 + L0, bp1 = P1 + L1, bp2 = P2 + L2;
  float C0 = PA0 + LA0 + 0.5f * (P0 * L1 - P1 * L0);
  float C1 = PA1 + LA1 + 0.5f * (P0 * L2 - P2 * L0);
  float C2 = PA2 + LA2 + 0.5f * (P1 * L2 - P2 * L1);

  if (p0 <= 999) {
#pragma unroll
    for (int i = 0; i < 4; ++i) {
      int p = p0 + i;
      if (p > 999) break;
      float n0 = bp0 + zs[p * 3 + 0] * scale;
      float n1 = bp1 + zs[p * 3 + 1] * scale;
      float n2 = bp2 + zs[p * 3 + 2] * scale;
      C0 += 0.5f * (bp0 * n1 - bp1 * n0);
      C1 += 0.5f * (bp0 * n2 - bp2 * n0);
      C2 += 0.5f * (bp1 * n2 - bp2 * n1);
      bp0 = n0; bp1 = n1; bp2 = n2;
      if (p % 50 == 0) {
        int s = p / 50;
        Cs[s][0] = C0; Cs[s][1] = C1; Cs[s][2] = C2;
      }
      int k = myfe[i];
      if (k >= 0) {
        earr[k][0] = bp0; earr[k][1] = bp1; earr[k][2] = bp2;
        earr[k][3] = C0;  earr[k][4] = C1;  earr[k][5] = C2;
      }
    }
  }
  __syncthreads();

  if (tid < 63) {
    int s = sc.starts[tid] / 50;
    half8 v = {};
    v[0] = (f16)earr[tid][0]; v[1] = (f16)earr[tid][1]; v[2] = (f16)earr[tid][2];
    v[3] = (f16)(earr[tid][3] - Cs[s][0]);
    v[4] = (f16)(earr[tid][4] - Cs[s][1]);
    v[5] = (f16)(earr[tid][5] - Cs[s][2]);
    half8 zz = {};
    half8* d = (half8*)(lsh + ((size_t)(tid + 1) * BATCH + b) * 64);
    d[0] = v;
#pragma unroll
    for (int q = 1; q < 8; ++q) d[q] = zz;
  } else if (tid == 63) {
    half8 zz = {};
    half8* d = (half8*)(lsh + (size_t)b * 64);
#pragma unroll
    for (int q = 0; q < 8; ++q) d[q] = zz;
  }
}

// ---------------------------------------------------------------------------
// Persistent chain (r19 sync topology, validated) with 512 threads / 8 waves
// per block (2 waves/SIMD) for latency hiding. Wave tiling 8 x (32 rows x
// 64 cols), acc[2][4]; staging 2 chunks/thread. Same kt/kk K-order per acc
// element -> bit-identical numerics.
// ---------------------------------------------------------------------------
__global__ __launch_bounds__(512, 1)
void chain_k(const ushort* __restrict__ lsh,
             const ushort* __restrict__ W1h, const ushort* __restrict__ W2h,
             const ushort* __restrict__ W3h,
             const float* __restrict__ b1, const float* __restrict__ b2,
             const float* __restrict__ b3, const float* __restrict__ Wout,
             ushort* __restrict__ act1a, ushort* __restrict__ act1b,
             ushort* __restrict__ act2a, ushort* __restrict__ act2b,
             ushort* __restrict__ Hall, float* __restrict__ outp,
             int* flags, Plan pl) {
  __shared__ ushort lds[32768];                   // 64KB: 2 x (X 16K | W 16K)
  char* ldsb = (char*)lds;
  const int tid = threadIdx.x;
  const int wv = tid >> 6, ln = tid & 63;
  const int slab = blockIdx.x;                    // 0..31; XCD = slab & 7
  const int bn0 = blockIdx.y * 128;               // col strip
  const int slot = slab >> 3;
  const int b0 = (slab & 7) * 128;                // batch-row base
  const size_t gr0 = (size_t)slab * 128;          // act-row base
  const int xcd = slab & 7;
  const int wr = wv >> 1, wc = wv & 1;            // 4 x 2 wave grid
  const int xr0 = wr * 32, nr0 = wc * 64;
  const int l15 = ln & 15, l4 = ln >> 4;
  int lbar = 0;

  f32x4 acc[2][4];

  auto gemm = [&](auto xsrc, const ushort* W, int ldw, int k0, int nk) {
#pragma unroll
    for (int mi = 0; mi < 2; ++mi)
#pragma unroll
      for (int ni = 0; ni < 4; ++ni) acc[mi][ni] = (f32x4){0.f, 0.f, 0.f, 0.f};

    auto stage = [&](int bi, int kt) {
#pragma unroll
      for (int i = 0; i < 2; ++i) {
        int qq = i * 512 + tid;                    // 0..1023 chunk id
        int r = qq >> 3, sl = qq & 7, ss = sl ^ (r & 7);
        const ushort* src = xsrc(kt, r, ss);
        __builtin_amdgcn_global_load_lds(
            (const __attribute__((address_space(1))) unsigned int*)src,
            (__attribute__((address_space(3))) unsigned int*)
                (ldsb + bi * 32768 + qq * 16), 16, 0, 0);
      }
#pragma unroll
      for (int i = 0; i < 2; ++i) {
        int qq = i * 512 + tid;
        int r = qq >> 3, sl = qq & 7, ss = sl ^ (r & 7);
        const ushort* src = W + (size_t)(bn0 + r) * ldw + kt * 64 + ss * 8;
        __builtin_amdgcn_global_load_lds(
            (const __attribute__((address_space(1))) unsigned int*)src,
            (__attribute__((address_space(3))) unsigned int*)
                (ldsb + bi * 32768 + 16384 + qq * 16), 16, 0, 0);
      }
    };

    stage(0, k0);
    int cur = 0;
    for (int kt = k0; kt < nk; ++kt) {
      if (kt + 1 < nk) {
        stage(cur ^ 1, kt + 1);                   // 4 more loads in flight
        asm volatile("s_waitcnt vmcnt(4)" ::: "memory");   // cur's 4 retired
      } else {
        asm volatile("s_waitcnt vmcnt(0)" ::: "memory");
      }
      __builtin_amdgcn_s_barrier();
      __builtin_amdgcn_sched_barrier(0);
#pragma unroll
      for (int kk = 0; kk < 2; ++kk) {
        half8 xf[2], wf[4];
#pragma unroll
        for (int mi = 0; mi < 2; ++mi) {
          int r = xr0 + mi * 16 + l15;
          int ss = (kk * 4 + l4) ^ (r & 7);
          xf[mi] = *(const half8*)(ldsb + cur * 32768 + r * 128 + ss * 16);
        }
#pragma unroll
        for (int ni = 0; ni < 4; ++ni) {
          int r = nr0 + ni * 16 + l15;
          int ss = (kk * 4 + l4) ^ (r & 7);
          wf[ni] = *(const half8*)(ldsb + cur * 32768 + 16384 + r * 128 + ss * 16);
        }
#pragma unroll
        for (int mi = 0; mi < 2; ++mi)
#pragma unroll
          for (int ni = 0; ni < 4; ++ni)
            acc[mi][ni] = __builtin_amdgcn_mfma_f32_16x16x32_f16(
                wf[ni], xf[mi], acc[mi][ni], 0, 0, 0);
      }
      __builtin_amdgcn_sched_barrier(0);
      asm volatile("s_waitcnt lgkmcnt(0)" ::: "memory");
      __builtin_amdgcn_s_barrier();
      cur ^= 1;
    }
  };

#define EPILOGUE_RELU(BIAS, DST)                                              \
  do {                                                                        \
    _Pragma("unroll")                                                         \
    for (int mi = 0; mi < 2; ++mi) {                                          \
      _Pragma("unroll")                                                       \
      for (int ni = 0; ni < 4; ++ni) {                                        \
        int col = bn0 + nr0 + ni * 16 + l4 * 4;                               \
        float4 bv = *(const float4*)&(BIAS)[col];                             \
        float bb[4] = {bv.x, bv.y, bv.z, bv.w};                               \
        union { f16 h[4]; u16x4 u; } cv;                                      \
        _Pragma("unroll")                                                     \
        for (int j4 = 0; j4 < 4; ++j4) {                                      \
          float v = acc[mi][ni][j4] + bb[j4];                                 \
          v = fmaxf(v, 0.f);                                                  \
          cv.h[j4] = (f16)v;                                                  \
        }                                                                     \
        *(u16x4*)&(DST)[(gr0 + xr0 + mi * 16 + l15) * 512 + col] = cv.u;      \
      }                                                                       \
    }                                                                         \
  } while (0)

#define SYNCSLAB()                                                            \
  do {                                                                        \
    ++lbar;                                                                   \
    asm volatile("s_waitcnt vmcnt(0)" ::: "memory");                          \
    __syncthreads();                                                          \
    if (tid == 0) {                                                           \
      __hip_atomic_fetch_add(&flags[slab], 1, __ATOMIC_RELAXED,               \
                             __HIP_MEMORY_SCOPE_AGENT);                       \
      while (__hip_atomic_load(&flags[slab], __ATOMIC_RELAXED,                \
                               __HIP_MEMORY_SCOPE_AGENT) < 4 * lbar)          \
        __builtin_amdgcn_s_sleep(2);                                          \
    }                                                                         \
    __syncthreads();                                                          \
  } while (0)

  for (int r = 0; r < pl.ng; ++r) {
    const bool active = (slot < pl.cnt[r]);
    if (active) {
      const int t = pl.tl[r][slot];
      const int gated = (t == pl.g[r]) ? 1 : 0;
      const ushort* lbase = lsh + (size_t)t * BATCH * 64;
      ushort* a1 = (r & 1) ? act1b : act1a;
      ushort* a2 = (r & 1) ? act2b : act2a;

      // ---- wait for carry producer (gated slab of round r-1, same XCD) ----
      if (r > 0) {
        __syncthreads();
        if (tid == 0) {
          while (__hip_atomic_load(&flags[32 + xcd], __ATOMIC_RELAXED,
                                   __HIP_MEMORY_SCOPE_AGENT) < 4 * r)
            __builtin_amdgcn_s_sleep(2);
        }
        __syncthreads();
      }

      // ---------------- layer 1 ----------------
      if (r == 0) {
        gemm([&](int kt, int rr, int ss) {
          (void)kt; return lbase + (size_t)(b0 + rr) * 64 + ss * 8;
        }, W1h, 576, 8, 9);
      } else {
        const ushort* carry = Hall + (size_t)pl.g[r - 1] * (BATCH * HID);
        gemm([&](int kt, int rr, int ss) {
          int b_ = b0 + rr;
          return (kt < 8) ? carry + (size_t)b_ * HID + kt * 64 + ss * 8
                          : lbase + (size_t)b_ * 64 + ss * 8;
        }, W1h, 576, 0, 9);
      }
      EPILOGUE_RELU(b1, a1);
      SYNCSLAB();

      // ---------------- layer 2 ----------------
      gemm([&](int kt, int rr, int ss) {
        return a1 + (gr0 + rr) * (size_t)HID + kt * 64 + ss * 8;
      }, W2h, 512, 0, 8);
      EPILOGUE_RELU(b2, a2);
      SYNCSLAB();

      // ---------------- layer 3: tanh; fused out-proj; gated -> Hall ------
      gemm([&](int kt, int rr, int ss) {
        return a2 + (gr0 + rr) * (size_t)HID + kt * 64 + ss * 8;
      }, W3h, 512, 0, 8);
      {
        float po[2][3];
#pragma unroll
        for (int mi = 0; mi < 2; ++mi) { po[mi][0] = 0.f; po[mi][1] = 0.f; po[mi][2] = 0.f; }
#pragma unroll
        for (int mi = 0; mi < 2; ++mi) {
#pragma unroll
          for (int ni = 0; ni < 4; ++ni) {
            int col = bn0 + nr0 + ni * 16 + l4 * 4;
            float4 bv = *(const float4*)&b3[col];
            float4 w0 = *(const float4*)&Wout[col];
            float4 w1 = *(const float4*)&Wout[512 + col];
            float4 w2 = *(const float4*)&Wout[1024 + col];
            float bb[4] = {bv.x, bv.y, bv.z, bv.w};
            float W0[4] = {w0.x, w0.y, w0.z, w0.w};
            float W1a[4] = {w1.x, w1.y, w1.z, w1.w};
            float W2a[4] = {w2.x, w2.y, w2.z, w2.w};
            union { f16 h[4]; u16x4 u; } cv;
#pragma unroll
            for (int j4 = 0; j4 < 4; ++j4) {
              float v = acc[mi][ni][j4] + bb[j4];
              float xc = fminf(fmaxf(v, -9.f), 9.f);
              float e = __expf(2.f * xc); v = (e - 1.f) / (e + 1.f);
              cv.h[j4] = (f16)v;
              po[mi][0] += v * W0[j4];
              po[mi][1] += v * W1a[j4];
              po[mi][2] += v * W2a[j4];
            }
            if (gated) {
              size_t hrow = (size_t)t * BATCH + b0 + xr0 + mi * 16 + l15;
              *(u16x4*)&Hall[hrow * 512 + col] = cv.u;
            }
          }
        }
#pragma unroll
        for (int mi = 0; mi < 2; ++mi) {
#pragma unroll
          for (int o = 0; o < 3; ++o) {
            float s = po[mi][o];
            s += __shfl_xor(s, 16);
            s += __shfl_xor(s, 32);
            po[mi][o] = s;
          }
          if (l4 == 0) {
            int row = b0 + xr0 + mi * 16 + l15;
            int y2 = blockIdx.y * 2 + wc;
            float* op = outp + (((size_t)y2 * WIN + t) * BATCH + row) * 3;
            op[0] = po[mi][0]; op[1] = po[mi][1]; op[2] = po[mi][2];
          }
        }
      }
      // ---- producer signal: gated slab announces Hall[g[r]] ready ----
      if (gated) {
        asm volatile("s_waitcnt vmcnt(0)" ::: "memory");
        __syncthreads();
        if (tid == 0)
          __hip_atomic_fetch_add(&flags[32 + xcd], 1, __ATOMIC_RELAXED,
                                 __HIP_MEMORY_SCOPE_AGENT);
      }
    }
  }
}

// ---------------------------------------------------------------------------
// out[b, t, o] = sum_{y2=0..7} outp[y2][t][b][o].
// ---------------------------------------------------------------------------
__global__ __launch_bounds__(256)
void out_sum(const float* __restrict__ outp, float* __restrict__ out) {
  int idx = blockIdx.x * 256 + threadIdx.x;       // (b*WIN + t)*3 + o
  if (idx >= BATCH * WIN * 3) return;
  int o = idx % 3, bt = idx / 3;
  int t = bt % WIN, b = bt / WIN;
  float s = 0.f;
#pragma unroll
  for (int y = 0; y < 8; ++y)
    s += outp[(((size_t)y * WIN + t) * BATCH + b) * 3 + o];
  out[idx] = s;
}

// ---------------------------------------------------------------------------
extern "C" void kernel_launch(void* const* d_in, const int* in_sizes, int n_in,
                              void* d_out, int out_size, void* d_ws, size_t ws_size,
                              hipStream_t stream) {
  (void)n_in; (void)out_size; (void)ws_size; (void)in_sizes;
  const float* z    = (const float*)d_in[0];
  const float* W1   = (const float*)d_in[1];
  const float* b1   = (const float*)d_in[2];
  const float* W2   = (const float*)d_in[3];
  const float* b2   = (const float*)d_in[4];
  const float* W3   = (const float*)d_in[5];
  const float* b3   = (const float*)d_in[6];
  const float* Wout = (const float*)d_in[7];
  float* out = (float*)d_out;

  // ---- replicate _static_schedule exactly (numpy linspace doubles) ----
  double tb[1000], tt[64], tu[20];
  {
    double sb = 1.0 / 999.0; for (int i = 0; i < 1000; ++i) tb[i] = i * sb; tb[999] = 1.0;
    double st = 1.0 / 63.0;  for (int k = 0; k < 64; ++k)  tt[k] = k * st;  tt[63] = 1.0;
    for (int j = 0; j < 20; ++j) tu[j] = tb[50 * j];
  }
  auto ssr = [](const double* a, int n, double v) -> int {
    int lo = 0, hi = n;
    while (lo < hi) { int mid = (lo + hi) >> 1; if (a[mid] <= v) lo = mid + 1; else hi = mid; }
    return lo - 1;
  };
  Sched sc; int gates[64];
  {
    int u_indices[20];
    for (int j = 0; j < 20; ++j) u_indices[j] = ssr(tb, 1000, tu[j]);
    double u_times[80]; int nut = 0; int last = -1;
    for (int k = 1; k < 64; ++k) {
      int it = ssr(tb, 1000, tt[k]);
      int iu = ssr(tu, 20, tt[k]); if (iu < 0) iu = 0;
      if (iu != last) { u_times[nut++] = tu[iu]; last = iu; }
      sc.starts[k - 1] = u_indices[iu];
      sc.ends[k - 1] = it;
    }
    u_times[nut++] = tt[63];
    int qh = 0;
    for (int k = 0; k < 64; ++k) {
      if (qh < nut && tt[k] >= u_times[qh]) { ++qh; gates[k] = 1; } else gates[k] = 0;
    }
  }
  int seg[64], g[64], ng = 0, jlast = -1;
  for (int t = 0; t < WIN; ++t) {
    seg[t] = jlast;
    if (gates[t]) { g[ng] = t; jlast = ng; ++ng; }
  }

  // ---- build device plan ----
  Plan pl; pl.ng = ng;
  for (int r = 0; r < ng && r < 24; ++r) {
    int cnt = 0;
    for (int t = 0; t < WIN && cnt < 4; ++t)
      if (seg[t] == r - 1) pl.tl[r][cnt++] = t;
    pl.cnt[r] = cnt;
    pl.g[r] = g[r];
    for (int i = cnt; i < 4; ++i) pl.tl[r][i] = 0;
  }

  // ---- workspace carve ----
  char* p = (char*)d_ws;
  int* flags    = (int*)p;    p += 64 * 4;
  ushort* lsh   = (ushort*)p; p += (size_t)WIN * BATCH * 64 * 2;       // 8.4 MB
  ushort* W1h   = (ushort*)p; p += (size_t)HID * 576 * 2;
  ushort* W2h   = (ushort*)p; p += (size_t)HID * HID * 2;
  ushort* W3h   = (ushort*)p; p += (size_t)HID * HID * 2;
  ushort* Hall  = (ushort*)p; p += (size_t)WIN * BATCH * HID * 2;      // 67 MB
  ushort* act1a = (ushort*)p; p += (size_t)4 * BATCH * HID * 2;        // 4.2 MB
  ushort* act1b = (ushort*)p; p += (size_t)4 * BATCH * HID * 2;
  ushort* act2a = (ushort*)p; p += (size_t)4 * BATCH * HID * 2;
  ushort* act2b = (ushort*)p; p += (size_t)4 * BATCH * HID * 2;
  float* outp   = (float*)p;  p += (size_t)8 * WIN * BATCH * 3 * 4;    // 6.3 MB

  hipMemsetAsync(flags, 0, 64 * 4, stream);

  float scale = (float)std::sqrt(1.0 / 999.0);
  prep<<<1024 + 400, 256, 0, stream>>>(z, sc, lsh, scale,
                                       W1, W2, W3, W1h, W2h, W3h);

  // ---- persistent chain: ONE launch, fine-grained producer flags ----
  chain_k<<<dim3(32, 4), 512, 0, stream>>>(lsh, W1h, W2h, W3h,
                                           b1, b2, b3, Wout,
                                           act1a, act1b, act2a, act2b,
                                           Hall, outp, flags, pl);

  out_sum<<<(BATCH * WIN * 3 + 255) / 256, 256, 0, stream>>>(outp, out);
}